// Round 14
// baseline (219.961 us; speedup 1.0000x reference)
//
#include <hip/hip_runtime.h>

typedef __bf16 bf16;
typedef bf16 bf16x4 __attribute__((ext_vector_type(4)));
typedef bf16 bf16x8 __attribute__((ext_vector_type(8)));
typedef float f32x4 __attribute__((ext_vector_type(4)));

#define MFMA16(A, B, C) __builtin_amdgcn_mfma_f32_16x16x32_bf16(A, B, C, 0, 0, 0)
#define NEG_BIG -30000.0f
#define LOG2E 1.44269504089f

// async 16B global->LDS: lds dest = wave-uniform base + lane*16
#define GLOAD_LDS16(gptr, lptr)                                                \
    __builtin_amdgcn_global_load_lds(                                          \
        (__attribute__((address_space(1))) void*)(gptr),                       \
        (__attribute__((address_space(3))) void*)(lptr), 16, 0, 0)

// ---------------------------------------------------------------------------
__global__ void mark_k(float* __restrict__ out, float val, int n) {
    int i = blockIdx.x * 256 + threadIdx.x;
    if (i < n) out[i] = val;
}

// ---------------------------------------------------------------------------
__global__ __launch_bounds__(256) void cvt_x_k(const float* __restrict__ src,
                                               bf16* __restrict__ dst, int n) {
    int i = (blockIdx.x * 256 + threadIdx.x) * 8;
    if (i >= n) return;
    float4 a = *(const float4*)&src[i];
    float4 b = *(const float4*)&src[i + 4];
    bf16x8 w;
    w[0] = (bf16)a.x; w[1] = (bf16)a.y; w[2] = (bf16)a.z; w[3] = (bf16)a.w;
    w[4] = (bf16)b.x; w[5] = (bf16)b.y; w[6] = (bf16)b.z; w[7] = (bf16)b.w;
    *(bf16x8*)&dst[i] = w;
}

// ---------------------------------------------------------------------------
// mask (int) -> additive f32 mask (0 or NEG_BIG). Runs after QKV GEMM;
// overwrites the then-dead wqkvT region.
// ---------------------------------------------------------------------------
__global__ void prep_mask_k(const int* __restrict__ mask, float* __restrict__ am) {
    int i = blockIdx.x * 256 + threadIdx.x;   // 0..4095
    am[i] = (mask[i] != 0) ? 0.0f : NEG_BIG;
}

// ---------------------------------------------------------------------------
__global__ __launch_bounds__(256) void transpose_cvt_tiled(
    const float* __restrict__ src, bf16* __restrict__ dst, int R, int C) {
    __shared__ float t[32][33];
    int tid = threadIdx.x, tx = tid & 31, ty = tid >> 5;
    int bx = blockIdx.x * 32, by = blockIdx.y * 32;
#pragma unroll
    for (int i = 0; i < 4; ++i) {
        int row = by + ty + i * 8;
        t[ty + i * 8][tx] = src[(size_t)row * C + bx + tx];
    }
    __syncthreads();
#pragma unroll
    for (int i = 0; i < 4; ++i) {
        int outrow = bx + ty + i * 8;
        dst[(size_t)outrow * R + by + tx] = (bf16)t[tx][ty + i * 8];
    }
}

// ---------------------------------------------------------------------------
// QKV GEMM (m97-style): 128x128, BK=32, async staging. Fused head-reshape;
// Q pre-scaled by 0.125*log2e (exp2-domain softmax); V^T stores bf16x4-packed.
// ---------------------------------------------------------------------------
__global__ __launch_bounds__(256) void gemm_qkv_v2(
    const bf16* __restrict__ A, const bf16* __restrict__ B,
    const float* __restrict__ bias, bf16* __restrict__ Qh,
    bf16* __restrict__ Kh, bf16* __restrict__ Vth) {
    __shared__ __align__(16) bf16 As[128 * 32];
    __shared__ __align__(16) bf16 Bs[128 * 32];
    int tid = threadIdx.x, lane = tid & 63, wave = tid >> 6;
    int quad = lane >> 4, l16 = lane & 15;
    int wr = wave >> 1, wc = wave & 1;
    int m0 = blockIdx.y * 128, n0 = blockIdx.x * 128;
    const int K = 768;
    const f32x4 fz = {0.f, 0.f, 0.f, 0.f};
    f32x4 acc[4][4];
#pragma unroll
    for (int mi = 0; mi < 4; ++mi)
#pragma unroll
        for (int nj = 0; nj < 4; ++nj) acc[mi][nj] = fz;
    const bf16* Ablk = A + (size_t)m0 * K;
    const bf16* Bblk = B + (size_t)n0 * K;
    int grow = tid >> 2, gcol = (tid & 3) * 8;

    for (int k0 = 0; k0 < K; k0 += 32) {
        __syncthreads();
#pragma unroll
        for (int j = 0; j < 2; ++j) {
            GLOAD_LDS16(&Ablk[(size_t)(grow + j * 64) * K + k0 + gcol],
                        &As[wave * 512 + j * 2048]);
            GLOAD_LDS16(&Bblk[(size_t)(grow + j * 64) * K + k0 + gcol],
                        &Bs[wave * 512 + j * 2048]);
        }
        __syncthreads();
        bf16x8 af[4], bfv[4];
#pragma unroll
        for (int t = 0; t < 4; ++t) {
            af[t]  = *(const bf16x8*)&As[(wr * 64 + t * 16 + l16) * 32 + quad * 8];
            bfv[t] = *(const bf16x8*)&Bs[(wc * 64 + t * 16 + l16) * 32 + quad * 8];
        }
#pragma unroll
        for (int mi = 0; mi < 4; ++mi)
#pragma unroll
            for (int nj = 0; nj < 4; ++nj)
                acc[mi][nj] = MFMA16(af[mi], bfv[nj], acc[mi][nj]);
    }

#pragma unroll
    for (int nj = 0; nj < 4; ++nj) {
        int col = n0 + wc * 64 + nj * 16 + l16;
        float bv = bias[col];
        int which = col / 768;
        int rr = col % 768;
        int h = rr >> 6, d = rr & 63;
#pragma unroll
        for (int mi = 0; mi < 4; ++mi) {
            int row_base = m0 + wr * 64 + mi * 16 + quad * 4;
            int b = row_base >> 11, l = row_base & 2047;
            size_t bh = (size_t)(b * 12 + h);
            if (which == 2) {
                bf16x4 pv;
#pragma unroll
                for (int r = 0; r < 4; ++r) pv[r] = (bf16)(acc[mi][nj][r] + bv);
                *(bf16x4*)&Vth[(bh * 64 + d) * 2048 + l] = pv;
            } else if (which == 0) {
#pragma unroll
                for (int r = 0; r < 4; ++r)
                    Qh[(bh * 2048 + l + r) * 64 + d] =
                        (bf16)((acc[mi][nj][r] + bv) * (0.125f * LOG2E));
            } else {
#pragma unroll
                for (int r = 0; r < 4; ++r)
                    Kh[(bh * 2048 + l + r) * 64 + d] = (bf16)(acc[mi][nj][r] + bv);
            }
        }
    }
}

// ---------------------------------------------------------------------------
// Out-projection GEMM v3: 128M x 64N tiles, 2 waves/block (128 thr),
// grid (12, 32) = 384 blocks. out(F32) = ctx (bf16) @ woutT^T + b_out.
// ---------------------------------------------------------------------------
__global__ __launch_bounds__(128) void gemm_out_v3(
    const bf16* __restrict__ A, const bf16* __restrict__ B,
    const float* __restrict__ bias, float* __restrict__ C) {
    __shared__ __align__(16) bf16 As[128 * 32];   // 8 KB
    __shared__ __align__(16) bf16 Bs[64 * 32];    // 4 KB
    int tid = threadIdx.x, lane = tid & 63, wave = tid >> 6;  // wave 0..1
    int quad = lane >> 4, l16 = lane & 15;
    int m0 = blockIdx.y * 128, n0 = blockIdx.x * 64;
    const int K = 768, N = 768;
    const f32x4 fz = {0.f, 0.f, 0.f, 0.f};
    f32x4 acc[4][4];
#pragma unroll
    for (int mi = 0; mi < 4; ++mi)
#pragma unroll
        for (int nj = 0; nj < 4; ++nj) acc[mi][nj] = fz;
    const bf16* Ablk = A + (size_t)m0 * K;
    const bf16* Bblk = B + (size_t)n0 * K;
    int grow = tid >> 2, gcol = (tid & 3) * 8;   // grow 0..31

    for (int k0 = 0; k0 < K; k0 += 32) {
        __syncthreads();
#pragma unroll
        for (int i = 0; i < 4; ++i)
            GLOAD_LDS16(&Ablk[(size_t)(i * 32 + grow) * K + k0 + gcol],
                        &As[i * 1024 + wave * 512]);
#pragma unroll
        for (int i = 0; i < 2; ++i)
            GLOAD_LDS16(&Bblk[(size_t)(i * 32 + grow) * K + k0 + gcol],
                        &Bs[i * 1024 + wave * 512]);
        __syncthreads();
        bf16x8 af[4], bfv[4];
#pragma unroll
        for (int t = 0; t < 4; ++t) {
            af[t]  = *(const bf16x8*)&As[(wave * 64 + t * 16 + l16) * 32 + quad * 8];
            bfv[t] = *(const bf16x8*)&Bs[(t * 16 + l16) * 32 + quad * 8];
        }
#pragma unroll
        for (int mi = 0; mi < 4; ++mi)
#pragma unroll
            for (int nj = 0; nj < 4; ++nj)
                acc[mi][nj] = MFMA16(af[mi], bfv[nj], acc[mi][nj]);
    }

#pragma unroll
    for (int nj = 0; nj < 4; ++nj) {
        int col = n0 + nj * 16 + l16;
        float bv = bias[col];
#pragma unroll
        for (int mi = 0; mi < 4; ++mi)
#pragma unroll
            for (int r = 0; r < 4; ++r) {
                int row = m0 + wave * 64 + mi * 16 + quad * 4 + r;
                C[(size_t)row * N + col] = acc[mi][nj][r] + bv;
            }
    }
}

// ---------------------------------------------------------------------------
// Flash attention v4: async swizzled K/V staging (global_load_lds, source-col
// XOR so LDS dest stays wave-uniform+lane*16), additive mask from global f32,
// exp2-domain softmax (Q pre-scaled by 0.125*log2e). LDS 36.5 KB -> 4 blk/CU.
// ---------------------------------------------------------------------------
#define SW(r, c8) ((r) * 64 + (((((c8) >> 3) ^ ((r) & 7))) << 3))
#define PLD 72

__global__ __launch_bounds__(128) void flash_attn(
    const bf16* __restrict__ Q, const bf16* __restrict__ K,
    const bf16* __restrict__ V, const float* __restrict__ addmask,
    bf16* __restrict__ ctx) {
    __shared__ __align__(16) bf16 Ks[2][64 * 64];
    __shared__ __align__(16) bf16 Vs[2][64 * 64];
    __shared__ __align__(16) bf16 Ps[2][16 * PLD];

    int tid = threadIdx.x, lane = tid & 63, wave = tid >> 6;
    int quad = lane >> 4, l16 = lane & 15;
    int bh = blockIdx.y, b = bh / 12;
    int q0 = blockIdx.x * 64 + wave * 32;

    bf16x8 aq[2][2];
#pragma unroll
    for (int qt = 0; qt < 2; ++qt) {
        const bf16* Qp = Q + ((size_t)bh * 2048 + q0 + qt * 16 + l16) * 64;
        aq[qt][0] = *(const bf16x8*)(Qp + quad * 8);
        aq[qt][1] = *(const bf16x8*)(Qp + 32 + quad * 8);
    }

    const float* am = addmask + b * 2048;
    const f32x4 fz = {0.f, 0.f, 0.f, 0.f};
    f32x4 o[2][4];
    float m_i[2], l_i[2];
#pragma unroll
    for (int qt = 0; qt < 2; ++qt) {
        m_i[qt] = NEG_BIG; l_i[qt] = 0.f;
#pragma unroll
        for (int dt = 0; dt < 4; ++dt) o[qt][dt] = fz;
    }

    int lrow8 = lane >> 3;          // 0..7
    int lc = lane & 7;              // source chunk before swizzle
    const bf16* Kbase = K + (size_t)bh * 2048 * 64;
    const bf16* Vbase = V + (size_t)bh * 64 * 2048;

    // Prologue: async-stage tile 0 into buffer 0 (source-col XOR swizzle)
#pragma unroll
    for (int i = 0; i < 4; ++i) {
        int r0 = wave * 32 + i * 8;
        int row = r0 + lrow8;
        int sc = (lc ^ (row & 7)) << 3;
        GLOAD_LDS16(&Kbase[(size_t)row * 64 + sc], &Ks[0][r0 * 64]);
        GLOAD_LDS16(&Vbase[(size_t)row * 2048 + sc], &Vs[0][r0 * 64]);
    }

    int p = 0;
    for (int kb = 0; kb < 2048; kb += 64) {
        __syncthreads();   // drains async (vmcnt) + prior LDS use

        if (kb + 64 < 2048) {
            int nb = kb + 64;
#pragma unroll
            for (int i = 0; i < 4; ++i) {
                int r0 = wave * 32 + i * 8;
                int row = r0 + lrow8;
                int sc = (lc ^ (row & 7)) << 3;
                GLOAD_LDS16(&Kbase[(size_t)(nb + row) * 64 + sc], &Ks[1 - p][r0 * 64]);
                GLOAD_LDS16(&Vbase[(size_t)row * 2048 + nb + sc], &Vs[1 - p][r0 * 64]);
            }
        }

        // S^T = K Q^T : key = ct*16 + quad*4 + r, qrow = l16  (exp2 domain)
        f32x4 s[2][4];
#pragma unroll
        for (int ct = 0; ct < 4; ++ct) {
            int krow = ct * 16 + l16;
            bf16x8 kf0 = *(const bf16x8*)&Ks[p][SW(krow, quad * 8)];
            bf16x8 kf1 = *(const bf16x8*)&Ks[p][SW(krow, 32 + quad * 8)];
#pragma unroll
            for (int qt = 0; qt < 2; ++qt) {
                f32x4 t = fz;
                t = MFMA16(kf0, aq[qt][0], t);
                t = MFMA16(kf1, aq[qt][1], t);
                s[qt][ct] = t;
            }
        }

#pragma unroll
        for (int ct = 0; ct < 4; ++ct) {
            float4 mv = *(const float4*)&am[kb + ct * 16 + quad * 4];
            float ma[4] = {mv.x, mv.y, mv.z, mv.w};
#pragma unroll
            for (int qt = 0; qt < 2; ++qt)
#pragma unroll
                for (int r = 0; r < 4; ++r) s[qt][ct][r] += ma[r];
        }

        float alpha[2];
#pragma unroll
        for (int qt = 0; qt < 2; ++qt) {
            float mx = NEG_BIG;
#pragma unroll
            for (int ct = 0; ct < 4; ++ct)
#pragma unroll
                for (int r = 0; r < 4; ++r) mx = fmaxf(mx, s[qt][ct][r]);
            mx = fmaxf(mx, __shfl_xor(mx, 16));
            mx = fmaxf(mx, __shfl_xor(mx, 32));
            float nm = fmaxf(m_i[qt], mx);
            alpha[qt] = exp2f(m_i[qt] - nm);
            m_i[qt] = nm;
            float sum = 0.f;
#pragma unroll
            for (int ct = 0; ct < 4; ++ct)
#pragma unroll
                for (int r = 0; r < 4; ++r) {
                    float pv = exp2f(s[qt][ct][r] - nm);
                    s[qt][ct][r] = pv;
                    sum += pv;
                }
            sum += __shfl_xor(sum, 16);
            sum += __shfl_xor(sum, 32);
            l_i[qt] = l_i[qt] * alpha[qt] + sum;
        }

#pragma unroll
        for (int qt = 0; qt < 2; ++qt) {
            float ab[4];
#pragma unroll
            for (int r = 0; r < 4; ++r)
                ab[r] = __shfl(alpha[qt], (lane & 48) | (quad * 4 + r));
#pragma unroll
            for (int dt = 0; dt < 4; ++dt)
#pragma unroll
                for (int r = 0; r < 4; ++r) o[qt][dt][r] *= ab[r];
        }

        bf16x8 vf[2][4];
#pragma unroll
        for (int ks = 0; ks < 2; ++ks)
#pragma unroll
            for (int dt = 0; dt < 4; ++dt)
                vf[ks][dt] = *(const bf16x8*)&Vs[p][SW(dt * 16 + l16, ks * 32 + quad * 8)];

#pragma unroll
        for (int qt = 0; qt < 2; ++qt) {
#pragma unroll
            for (int ct = 0; ct < 4; ++ct) {
                bf16x4 pk;
#pragma unroll
                for (int r = 0; r < 4; ++r) pk[r] = (bf16)s[qt][ct][r];
                *(bf16x4*)&Ps[wave][l16 * PLD + ct * 16 + quad * 4] = pk;
            }
#pragma unroll
            for (int ks = 0; ks < 2; ++ks) {
                bf16x8 ap = *(const bf16x8*)&Ps[wave][l16 * PLD + ks * 32 + quad * 8];
#pragma unroll
                for (int dt = 0; dt < 4; ++dt)
                    o[qt][dt] = MFMA16(ap, vf[ks][dt], o[qt][dt]);
            }
        }
        p ^= 1;
    }

    int h = bh % 12;
#pragma unroll
    for (int qt = 0; qt < 2; ++qt) {
        float linv[4];
#pragma unroll
        for (int r = 0; r < 4; ++r)
            linv[r] = 1.0f / __shfl(l_i[qt], (lane & 48) | (quad * 4 + r));
#pragma unroll
        for (int dt = 0; dt < 4; ++dt)
#pragma unroll
            for (int r = 0; r < 4; ++r) {
                int qrow = q0 + qt * 16 + quad * 4 + r;
                ctx[((size_t)b * 2048 + qrow) * 768 + h * 64 + dt * 16 + l16] =
                    (bf16)(o[qt][dt][r] * linv[r]);
            }
    }
}

// ---------------------------------------------------------------------------
extern "C" void kernel_launch(void* const* d_in, const int* in_sizes, int n_in,
                              void* d_out, int out_size, void* d_ws, size_t ws_size,
                              hipStream_t stream) {
    float* out = (float*)d_out;   // f32 output (validated round 10)

    const float* x = nullptr; const int* mask = nullptr;
    const float* w_qkv = nullptr; const float* b_qkv = nullptr;
    const float* w_out = nullptr; const float* b_out = nullptr;
    int found = 0;
    for (int i = 0; i < n_in; ++i) {
        switch (in_sizes[i]) {
            case 3145728: x     = (const float*)d_in[i]; found |= 1;  break;
            case 4096:    mask  = (const int*)  d_in[i]; found |= 2;  break;
            case 1769472: w_qkv = (const float*)d_in[i]; found |= 4;  break;
            case 2304:    b_qkv = (const float*)d_in[i]; found |= 8;  break;
            case 589824:  w_out = (const float*)d_in[i]; found |= 16; break;
            case 768:     b_out = (const float*)d_in[i]; found |= 32; break;
        }
    }
    if (found != 63) {
        mark_k<<<(out_size + 255) / 256, 256, 0, stream>>>(
            out, 200.0f + (float)found, out_size);
        return;
    }

    const int M = 4096, D = 768, N3 = 2304;
    const size_t HEADS_ELEMS = (size_t)24 * 2048 * 64;  // 3,145,728

    // Workspace (23.6 MB, proven). d_out moonlights as Qh + xb.
    bf16* ws    = (bf16*)d_ws;
    bf16* Kh    = ws;
    bf16* Vth   = Kh + HEADS_ELEMS;
    bf16* ctx   = Vth + HEADS_ELEMS;
    bf16* wqkvT = ctx + (size_t)M * D;
    bf16* woutT = wqkvT + (size_t)N3 * D;
    bf16* Qh    = (bf16*)d_out;
    bf16* xb    = (bf16*)d_out + HEADS_ELEMS;
    float* addmask = (float*)wqkvT;   // aliases wqkvT (dead after QKV GEMM)

    cvt_x_k<<<(M * D / 8 + 255) / 256, 256, 0, stream>>>(x, xb, M * D);
    transpose_cvt_tiled<<<dim3(2304 / 32, 768 / 32), 256, 0, stream>>>(
        w_qkv, wqkvT, 768, 2304);
    transpose_cvt_tiled<<<dim3(768 / 32, 768 / 32), 256, 0, stream>>>(
        w_out, woutT, 768, 768);

    gemm_qkv_v2<<<dim3(N3 / 128, M / 128), 256, 0, stream>>>(
        xb, wqkvT, b_qkv, Qh, Kh, Vth);

    prep_mask_k<<<16, 256, 0, stream>>>(mask, addmask);  // wqkvT now dead

    flash_attn<<<dim3(2048 / 64, 24), 128, 0, stream>>>(Qh, Kh, Vth, addmask, ctx);

    gemm_out_v3<<<dim3(D / 64, M / 128), 128, 0, stream>>>(
        ctx, woutT, b_out, out);
}